// Round 1
// baseline (331.061 us; speedup 1.0000x reference)
//
#include <hip/hip_runtime.h>

#define DFEAT 128
#define HID 16

__device__ __forceinline__ float bf2f(unsigned v) { return __uint_as_float(v << 16); }
__device__ __forceinline__ unsigned short f2bf(float f) {
    unsigned u = __float_as_uint(f);
    return (unsigned short)((u + 0x7FFFu + ((u >> 16) & 1u)) >> 16);
}

// flags[0] = 1 if float tensors are bf16, 0 if f32
// flags[1] = 1 if edge_index is int64, 0 if int32
__global__ void k_detect(const unsigned short* __restrict__ x,
                         const int* __restrict__ ei,
                         int* __restrict__ flags) {
    if (threadIdx.x == 0 && blockIdx.x == 0) {
        // bf16 test: even u16 words. If bf16, these are bf16(N(0,1)) -> exponent
        // field in a narrow band. If f32, they are low mantissa bits -> uniform.
        int pass = 0;
        for (int i = 0; i < 128; i++) {
            unsigned short v = x[2 * i];
            int e = (v >> 7) & 0xFF;
            if (v == 0 || (e >= 110 && e <= 130)) pass++;
        }
        flags[0] = (pass >= 100) ? 1 : 0;
        // int64 test: odd int32 words are the high halves (all zero, values < 2^31)
        int zeros = 0;
        for (int i = 0; i < 64; i++)
            if (ei[2 * i + 1] == 0) zeros++;
        flags[1] = (zeros >= 60) ? 1 : 0;
    }
}

// p1 = x @ w1_rel, q1 = x @ w1_root   (16 nodes per block, 256 threads)
__global__ __launch_bounds__(256) void k_lin1(const void* __restrict__ xv,
                                              const void* __restrict__ wrel,
                                              const void* __restrict__ wroot,
                                              float* __restrict__ p1,
                                              float* __restrict__ q1,
                                              const int* __restrict__ flags,
                                              int N) {
    __shared__ float xs[16][DFEAT + 1];     // +1 pad: break stride-128 bank aliasing
    __shared__ float swr[DFEAT * HID];
    __shared__ float swo[DFEAT * HID];

    const int t = threadIdx.x;
    const int bf = flags[0];
    const int nb = blockIdx.x * 16;

    // stage weights (2048 f32 each)
    if (bf) {
        const unsigned short* a = (const unsigned short*)wrel;
        const unsigned short* b = (const unsigned short*)wroot;
        for (int r = t; r < DFEAT * HID; r += 256) {
            swr[r] = bf2f(a[r]);
            swo[r] = bf2f(b[r]);
        }
    } else {
        const float* a = (const float*)wrel;
        const float* b = (const float*)wroot;
        for (int r = t; r < DFEAT * HID; r += 256) {
            swr[r] = a[r];
            swo[r] = b[r];
        }
    }

    // stage x tile: 16 rows x 128, each thread loads 8 contiguous elements
    {
        const int row = (t * 8) >> 7;
        const int col = (t * 8) & 127;
        const int n = nb + row;
        if (n < N) {
            if (bf) {
                const unsigned short* xp = (const unsigned short*)xv;
                uint4 v = *(const uint4*)(xp + (size_t)n * DFEAT + col);
                xs[row][col + 0] = bf2f(v.x & 0xFFFFu);
                xs[row][col + 1] = bf2f(v.x >> 16);
                xs[row][col + 2] = bf2f(v.y & 0xFFFFu);
                xs[row][col + 3] = bf2f(v.y >> 16);
                xs[row][col + 4] = bf2f(v.z & 0xFFFFu);
                xs[row][col + 5] = bf2f(v.z >> 16);
                xs[row][col + 6] = bf2f(v.w & 0xFFFFu);
                xs[row][col + 7] = bf2f(v.w >> 16);
            } else {
                const float* xp = (const float*)xv;
                const float4* s = (const float4*)(xp + (size_t)n * DFEAT + col);
                float4 v0 = s[0], v1 = s[1];
                xs[row][col + 0] = v0.x; xs[row][col + 1] = v0.y;
                xs[row][col + 2] = v0.z; xs[row][col + 3] = v0.w;
                xs[row][col + 4] = v1.x; xs[row][col + 5] = v1.y;
                xs[row][col + 6] = v1.z; xs[row][col + 7] = v1.w;
            }
        }
    }
    __syncthreads();

    const int i = t >> 4;   // node within tile
    const int j = t & 15;   // output column
    float accp = 0.f, accq = 0.f;
#pragma unroll 8
    for (int k = 0; k < DFEAT; k++) {
        float xvv = xs[i][k];
        accp += xvv * swr[k * HID + j];
        accq += xvv * swo[k * HID + j];
    }
    const int n2 = nb + i;
    if (n2 < N) {
        p1[(size_t)n2 * HID + j] = accp;
        q1[(size_t)n2 * HID + j] = accq;
    }
}

// agg[dst] += p[src], one thread per (edge, channel)
__global__ __launch_bounds__(256) void k_scatter(const int* __restrict__ ei,
                                                 const float* __restrict__ p,
                                                 float* __restrict__ agg,
                                                 const int* __restrict__ flags,
                                                 int E) {
    const int gid = blockIdx.x * 256 + threadIdx.x;
    if (gid >= E * HID) return;
    const int e = gid >> 4;
    const int j = gid & 15;
    int src, dst;
    if (flags[1]) {  // int64 storage: low words at even offsets
        src = ei[2 * e];
        dst = ei[2 * (E + e)];
    } else {
        src = ei[e];
        dst = ei[E + e];
    }
    atomicAdd(agg + (size_t)dst * HID + j, p[(size_t)src * HID + j]);
}

// h = relu(agg1 + q1 + b1); p2 = h @ w2_rel; q2 = h @ w2_root
__global__ __launch_bounds__(256) void k_mid(const float* __restrict__ agg1,
                                             const float* __restrict__ q1,
                                             const void* __restrict__ b1,
                                             const void* __restrict__ w2rel,
                                             const void* __restrict__ w2root,
                                             float* __restrict__ p2,
                                             float* __restrict__ q2,
                                             const int* __restrict__ flags,
                                             int N) {
    __shared__ float swr[HID * HID];
    __shared__ float swo[HID * HID];
    __shared__ float sb[HID];
    const int t = threadIdx.x;
    const int bf = flags[0];
    if (bf) {
        const unsigned short* a = (const unsigned short*)w2rel;
        const unsigned short* b = (const unsigned short*)w2root;
        const unsigned short* c = (const unsigned short*)b1;
        if (t < HID * HID) { swr[t] = bf2f(a[t]); swo[t] = bf2f(b[t]); }
        if (t < HID) sb[t] = bf2f(c[t]);
    } else {
        const float* a = (const float*)w2rel;
        const float* b = (const float*)w2root;
        const float* c = (const float*)b1;
        if (t < HID * HID) { swr[t] = a[t]; swo[t] = b[t]; }
        if (t < HID) sb[t] = c[t];
    }
    __syncthreads();

    const int n = blockIdx.x * 256 + t;
    if (n >= N) return;

    float h[HID];
    const float4* ap = (const float4*)(agg1 + (size_t)n * HID);
    const float4* qp = (const float4*)(q1 + (size_t)n * HID);
#pragma unroll
    for (int r = 0; r < 4; r++) {
        float4 av = ap[r], qv = qp[r];
        h[4 * r + 0] = fmaxf(av.x + qv.x + sb[4 * r + 0], 0.f);
        h[4 * r + 1] = fmaxf(av.y + qv.y + sb[4 * r + 1], 0.f);
        h[4 * r + 2] = fmaxf(av.z + qv.z + sb[4 * r + 2], 0.f);
        h[4 * r + 3] = fmaxf(av.w + qv.w + sb[4 * r + 3], 0.f);
    }

    float op[HID], oq[HID];
#pragma unroll
    for (int j = 0; j < HID; j++) {
        float sp = 0.f, sq = 0.f;
#pragma unroll
        for (int k = 0; k < HID; k++) {
            sp += h[k] * swr[k * HID + j];
            sq += h[k] * swo[k * HID + j];
        }
        op[j] = sp; oq[j] = sq;
    }
    float4* pp = (float4*)(p2 + (size_t)n * HID);
    float4* qq = (float4*)(q2 + (size_t)n * HID);
#pragma unroll
    for (int r = 0; r < 4; r++) {
        pp[r] = make_float4(op[4 * r], op[4 * r + 1], op[4 * r + 2], op[4 * r + 3]);
        qq[r] = make_float4(oq[4 * r], oq[4 * r + 1], oq[4 * r + 2], oq[4 * r + 3]);
    }
}

// out = log_softmax(agg2 + q2 + b2)
__global__ __launch_bounds__(256) void k_out(const float* __restrict__ agg2,
                                             const float* __restrict__ q2,
                                             const void* __restrict__ b2,
                                             void* __restrict__ out,
                                             const int* __restrict__ flags,
                                             int N) {
    __shared__ float sb[HID];
    const int t = threadIdx.x;
    const int bf = flags[0];
    if (t < HID) sb[t] = bf ? bf2f(((const unsigned short*)b2)[t]) : ((const float*)b2)[t];
    __syncthreads();

    const int n = blockIdx.x * 256 + t;
    if (n >= N) return;

    float o[HID];
    const float4* ap = (const float4*)(agg2 + (size_t)n * HID);
    const float4* qp = (const float4*)(q2 + (size_t)n * HID);
#pragma unroll
    for (int r = 0; r < 4; r++) {
        float4 av = ap[r], qv = qp[r];
        o[4 * r + 0] = av.x + qv.x + sb[4 * r + 0];
        o[4 * r + 1] = av.y + qv.y + sb[4 * r + 1];
        o[4 * r + 2] = av.z + qv.z + sb[4 * r + 2];
        o[4 * r + 3] = av.w + qv.w + sb[4 * r + 3];
    }
    float m = o[0];
#pragma unroll
    for (int j = 1; j < HID; j++) m = fmaxf(m, o[j]);
    float s = 0.f;
#pragma unroll
    for (int j = 0; j < HID; j++) s += __expf(o[j] - m);
    const float l = m + __logf(s);

    if (bf) {
        unsigned short us[HID];
#pragma unroll
        for (int j = 0; j < HID; j++) us[j] = f2bf(o[j] - l);
        uint4 v0, v1;
        v0.x = us[0] | ((unsigned)us[1] << 16);
        v0.y = us[2] | ((unsigned)us[3] << 16);
        v0.z = us[4] | ((unsigned)us[5] << 16);
        v0.w = us[6] | ((unsigned)us[7] << 16);
        v1.x = us[8] | ((unsigned)us[9] << 16);
        v1.y = us[10] | ((unsigned)us[11] << 16);
        v1.z = us[12] | ((unsigned)us[13] << 16);
        v1.w = us[14] | ((unsigned)us[15] << 16);
        uint4* op = (uint4*)out;
        op[(size_t)n * 2 + 0] = v0;
        op[(size_t)n * 2 + 1] = v1;
    } else {
        float* fo = (float*)out;
        float4* op = (float4*)(fo + (size_t)n * HID);
#pragma unroll
        for (int r = 0; r < 4; r++)
            op[r] = make_float4(o[4 * r] - l, o[4 * r + 1] - l, o[4 * r + 2] - l, o[4 * r + 3] - l);
    }
}

extern "C" void kernel_launch(void* const* d_in, const int* in_sizes, int n_in,
                              void* d_out, int out_size, void* d_ws, size_t ws_size,
                              hipStream_t stream) {
    const void* x      = d_in[0];
    const int*  ei     = (const int*)d_in[1];
    const void* w1_rel = d_in[2];
    const void* w1_root= d_in[3];
    const void* b1     = d_in[4];
    const void* w2_rel = d_in[5];
    const void* w2_root= d_in[6];
    const void* b2     = d_in[7];

    const int N = in_sizes[0] / DFEAT;   // 100000
    const int E = in_sizes[1] / 2;       // 1600000 (element count is dtype-agnostic)

    float* ws  = (float*)d_ws;
    float* p1   = ws;
    float* q1   = p1 + (size_t)N * HID;
    float* agg1 = q1 + (size_t)N * HID;
    float* p2   = agg1 + (size_t)N * HID;
    float* q2   = p2 + (size_t)N * HID;
    float* agg2 = q2 + (size_t)N * HID;
    int* flags  = (int*)(agg2 + (size_t)N * HID);

    k_detect<<<1, 64, 0, stream>>>((const unsigned short*)x, ei, flags);

    hipMemsetAsync(agg1, 0, (size_t)N * HID * sizeof(float), stream);
    hipMemsetAsync(agg2, 0, (size_t)N * HID * sizeof(float), stream);

    k_lin1<<<(N + 15) / 16, 256, 0, stream>>>(x, w1_rel, w1_root, p1, q1, flags, N);

    const int scat_blocks = (E * HID + 255) / 256;
    k_scatter<<<scat_blocks, 256, 0, stream>>>(ei, p1, agg1, flags, E);

    k_mid<<<(N + 255) / 256, 256, 0, stream>>>(agg1, q1, b1, w2_rel, w2_root, p2, q2, flags, N);

    k_scatter<<<scat_blocks, 256, 0, stream>>>(ei, p2, agg2, flags, E);

    k_out<<<(N + 255) / 256, 256, 0, stream>>>(agg2, q2, b2, d_out, flags, N);
}